// Round 3
// baseline (1317.649 us; speedup 1.0000x reference)
//
#include <hip/hip_runtime.h>
#include <hip/hip_bf16.h>
#include <math.h>

#define B 8
#define S 4096
#define D 256
#define H 256
#define FEAT 1794
#define R (B*S)
#define DH (D*H)
#define TM 16
#define NCH 32   // s-chunks for e partial reduction

// ws layout (float offsets) — total ~959K floats ~= 3.84 MB
#define OFF_WT    0                        // 5 blocks [c][cq][cm][aq][am], each D*H
#define OFF_WC    (OFF_WT + 5*DH)          // B*D*H combined c-weights
#define OFF_VQ    (OFF_WC + B*DH)          // B*D
#define OFF_VM    (OFF_VQ + B*D)           // B*D
#define OFF_HB    (OFF_VM + B*D)           // B*H
#define OFF_M     (OFF_HB + B*H)           // B*D
#define OFF_EP    (OFF_M + B*D)            // NCH*B*D
#define OFF_SC    (OFF_EP + NCH*B*D)       // R

__device__ __forceinline__ float waveReduceSum(float v) {
  #pragma unroll
  for (int off = 32; off; off >>= 1) v += __shfl_xor(v, off, 64);
  return v;
}

// Transpose 5 D-wide w1 column-blocks into [k][h] layout.
// Block order: 0=c(col 0), 1=c*q(3D), 2=c*m(4D), 3=|c-q|(5D), 4=|c-m|(6D)
__global__ void k_wt(const float* __restrict__ w1, float* __restrict__ wt) {
  int t = blockIdx.x * 256 + threadIdx.x;   // 5*65536 total
  int blk = t >> 16;
  int k = (t >> 8) & 255, h = t & 255;
  const int colOff[5] = {0, 3*D, 4*D, 5*D, 6*D};
  wt[t] = w1[h*FEAT + colOff[blk] + k];
}

// Once per call: vq = A@q, m := q.
__global__ void k_p0(const float* __restrict__ q, const float* __restrict__ A,
                     float* __restrict__ vq, float* __restrict__ mcur) {
  int b = blockIdx.x, t = threadIdx.x;
  __shared__ float qs[D];
  qs[t] = q[b*D + t];
  __syncthreads();
  float acc = 0.f;
  for (int d = 0; d < D; d++) acc += A[t*D + d] * qs[d];
  vq[b*D + t] = acc;
  mcur[b*D + t] = qs[t];
}

// Per hop: vm = A@m, hbase = b1 + q@W1q^T + m@W1m^T.
__global__ void k_pm(const float* __restrict__ A, const float* __restrict__ w1,
                     const float* __restrict__ b1, const float* __restrict__ q,
                     const float* __restrict__ mcur,
                     float* __restrict__ vm, float* __restrict__ hbase) {
  int b = blockIdx.x, t = threadIdx.x;
  __shared__ float msh[D], qsh[D];
  msh[t] = mcur[b*D + t];
  qsh[t] = q[b*D + t];
  __syncthreads();
  float acc = 0.f;
  for (int d = 0; d < D; d++) acc += A[t*D + d] * msh[d];
  vm[b*D + t] = acc;
  float hb = b1[t];
  const float* w1r = w1 + t*FEAT;
  for (int d = 0; d < D; d++) hb += qsh[d]*w1r[2*D + d] + msh[d]*w1r[D + d];
  hbase[b*H + t] = hb;
}

// Per hop: WC[b][k][h] = Wc[k,h] + q[b,k]*Wcq[k,h] + m[b,k]*Wcm[k,h]
__global__ void k_comb(const float* __restrict__ wt, const float* __restrict__ q,
                       const float* __restrict__ mcur, float* __restrict__ wc) {
  int t = blockIdx.x * 256 + threadIdx.x;  // B*D*H
  int b = t >> 16;
  int k = (t >> 8) & 255;
  int kh = t & 65535;
  wc[t] = wt[kh] + q[b*D + k]*wt[DH + kh] + mcur[b*D + k]*wt[2*DH + kh];
}

// Per-hop fused GEMM (K=768) + rank-1 dot terms + tanh + w2-dot -> scores[r].
// One h-column per thread (t == h).
__global__ __launch_bounds__(256) void k_score(
    const float* __restrict__ c, const float* __restrict__ q,
    const float* __restrict__ mcur,
    const float* __restrict__ wcomb, const float* __restrict__ wt,
    const float* __restrict__ vq, const float* __restrict__ vm,
    const float* __restrict__ hbase, const float* __restrict__ w1,
    const float* __restrict__ w2, const float* __restrict__ b2,
    float* __restrict__ scores) {
  __shared__ float cs[TM][D], aqv[TM][D], amv[TM][D];
  __shared__ float redq[4][TM], redm[4][TM], red2[4][TM];
  const int t = threadIdx.x;
  const int r0 = blockIdx.x * TM;
  const int b = r0 >> 12;   // r0 / S
  const float qd  = q[b*D + t];
  const float md  = mcur[b*D + t];
  const float vqd = vq[b*D + t];
  const float vmd = vm[b*D + t];
  #pragma unroll
  for (int j = 0; j < TM; j++) {
    float cvj = c[(r0 + j)*D + t];
    cs[j][t]  = cvj;
    aqv[j][t] = fabsf(cvj - qd);
    amv[j][t] = fabsf(cvj - md);
    float pq = waveReduceSum(cvj * vqd);
    float pm = waveReduceSum(cvj * vmd);
    if ((t & 63) == 0) { redq[t >> 6][j] = pq; redm[t >> 6][j] = pm; }
  }
  __syncthreads();

  const float* wcp = wcomb + b*DH + t;   // column t, stride H over k
  const float* waq = wt + 3*DH + t;
  const float* wam = wt + 4*DH + t;
  float acc[TM];
  #pragma unroll
  for (int j = 0; j < TM; j++) acc[j] = 0.f;

  for (int k = 0; k < D; k += 4) {
    float wc_[4], wa_[4], wm_[4];
    #pragma unroll
    for (int kk = 0; kk < 4; kk++) {
      wc_[kk] = wcp[(k + kk)*H];
      wa_[kk] = waq[(k + kk)*H];
      wm_[kk] = wam[(k + kk)*H];
    }
    #pragma unroll
    for (int j = 0; j < TM; j++) {
      const float4 c4 = *(const float4*)(&cs[j][k]);
      const float4 a4 = *(const float4*)(&aqv[j][k]);
      const float4 m4 = *(const float4*)(&amv[j][k]);
      acc[j] += c4.x*wc_[0] + c4.y*wc_[1] + c4.z*wc_[2] + c4.w*wc_[3]
              + a4.x*wa_[0] + a4.y*wa_[1] + a4.z*wa_[2] + a4.w*wa_[3]
              + m4.x*wm_[0] + m4.y*wm_[1] + m4.z*wm_[2] + m4.w*wm_[3];
    }
  }

  const float hb  = hbase[b*H + t];
  const float wdq = w1[t*FEAT + 7*D];
  const float wdm = w1[t*FEAT + 7*D + 1];
  const float w2t = w2[t];
  #pragma unroll
  for (int j = 0; j < TM; j++) {
    float dq = redq[0][j] + redq[1][j] + redq[2][j] + redq[3][j];
    float dm = redm[0][j] + redm[1][j] + redm[2][j] + redm[3][j];
    float th = tanhf(acc[j] + hb + dq*wdq + dm*wdm);
    float v = waveReduceSum(th * w2t);
    if ((t & 63) == 0) red2[t >> 6][j] = v;
  }
  __syncthreads();
  if (t < TM) scores[r0 + t] = red2[0][t] + red2[1][t] + red2[2][t] + red2[3][t] + b2[0];
}

// Masked softmax over S per batch; writes att (zeros beyond len).
__global__ void k_soft(const float* __restrict__ scores, const int* __restrict__ len_c,
                       float* __restrict__ att) {
  const int b = blockIdx.x, t = threadIdx.x;
  const int len = len_c[b];
  __shared__ float rbuf[4];
  const float* sc = scores + b*S;
  float mx = -1e30f;
  for (int s = t; s < len; s += 256) mx = fmaxf(mx, sc[s]);
  #pragma unroll
  for (int off = 32; off; off >>= 1) mx = fmaxf(mx, __shfl_xor(mx, off, 64));
  if ((t & 63) == 0) rbuf[t >> 6] = mx;
  __syncthreads();
  mx = fmaxf(fmaxf(rbuf[0], rbuf[1]), fmaxf(rbuf[2], rbuf[3]));
  __syncthreads();
  float sum = 0.f;
  for (int s = t; s < len; s += 256) sum += expf(sc[s] - mx);
  sum = waveReduceSum(sum);
  if ((t & 63) == 0) rbuf[t >> 6] = sum;
  __syncthreads();
  sum = rbuf[0] + rbuf[1] + rbuf[2] + rbuf[3];
  const float inv = 1.f / sum;
  float* ab = att + b*S;
  for (int s = t; s < S; s += 256) ab[s] = (s < len) ? expf(sc[s] - mx) * inv : 0.f;
}

// epart[ch,b,d] = sum_{s in chunk, s<len} att[s]*c[b,s,d]
__global__ void k_epart(const float* __restrict__ c, const float* __restrict__ att,
                        const int* __restrict__ len_c, float* __restrict__ epart) {
  const int b = blockIdx.x >> 5, ch = blockIdx.x & 31;
  const int t = threadIdx.x;
  const int len = len_c[b];
  const int s0 = ch * (S / NCH);
  const int send = min(s0 + (S / NCH), len);
  float acc = 0.f;
  const float* ab = att + b*S;
  int s = s0;
  for (; s + 3 < send; s += 4) {
    float a0 = ab[s], a1 = ab[s+1], a2 = ab[s+2], a3 = ab[s+3];
    const float* cp = c + (b*S + s)*D + t;
    acc += a0*cp[0] + a1*cp[D] + a2*cp[2*D] + a3*cp[3*D];
  }
  for (; s < send; s++) acc += ab[s] * c[(b*S + s)*D + t];
  epart[(ch*B + b)*D + t] = acc;
}

// GRU cell: e = sum(epart), gates, update mcur (and final output on last hop).
__global__ void k_gru(const float* __restrict__ wih, const float* __restrict__ whh,
                      const float* __restrict__ bih, const float* __restrict__ bhh,
                      const float* __restrict__ epart, float* __restrict__ mcur,
                      float* __restrict__ out, const int write_out) {
  const int b = blockIdx.x, t = threadIdx.x;
  __shared__ float es[D], ms[D], gis[3*D], ghs[3*D];
  float e = 0.f;
  #pragma unroll
  for (int ch = 0; ch < NCH; ch++) e += epart[(ch*B + b)*D + t];
  es[t] = e;
  ms[t] = mcur[b*D + t];
  __syncthreads();
  #pragma unroll
  for (int jj = 0; jj < 3; jj++) {
    const int j = jj*D + t;
    float gi = bih[j], gh = bhh[j];
    const float* wi = wih + j*D;
    const float* wh = whh + j*D;
    for (int d = 0; d < D; d++) { gi += es[d]*wi[d]; gh += ms[d]*wh[d]; }
    gis[j] = gi; ghs[j] = gh;
  }
  __syncthreads();
  float rr = 1.f / (1.f + expf(-(gis[t] + ghs[t])));
  float zz = 1.f / (1.f + expf(-(gis[D + t] + ghs[D + t])));
  float nn = tanhf(gis[2*D + t] + rr * ghs[2*D + t]);
  float mnew = (1.f - zz)*nn + zz*ms[t];
  mcur[b*D + t] = mnew;
  if (write_out) out[b*D + t] = mnew;
}

extern "C" void kernel_launch(void* const* d_in, const int* in_sizes, int n_in,
                              void* d_out, int out_size, void* d_ws, size_t ws_size,
                              hipStream_t stream) {
  const float* c   = (const float*)d_in[0];
  const float* q   = (const float*)d_in[1];
  const int*   len = (const int*)d_in[2];
  const float* A   = (const float*)d_in[3];
  const float* w1  = (const float*)d_in[4];
  const float* b1  = (const float*)d_in[5];
  const float* w2  = (const float*)d_in[6];
  const float* b2  = (const float*)d_in[7];
  const float* wih = (const float*)d_in[8];
  const float* whh = (const float*)d_in[9];
  const float* bih = (const float*)d_in[10];
  const float* bhh = (const float*)d_in[11];
  float* out = (float*)d_out;
  float* ws  = (float*)d_ws;

  float* WT    = ws + OFF_WT;
  float* WC    = ws + OFF_WC;
  float* vq    = ws + OFF_VQ;
  float* vm    = ws + OFF_VM;
  float* hbase = ws + OFF_HB;
  float* mcur  = ws + OFF_M;
  float* epart = ws + OFF_EP;
  float* sc    = ws + OFF_SC;

  k_wt<<<5*DH/256, 256, 0, stream>>>(w1, WT);
  k_p0<<<B, 256, 0, stream>>>(q, A, vq, mcur);

  for (int it = 0; it < 3; ++it) {
    k_pm<<<B, 256, 0, stream>>>(A, w1, b1, q, mcur, vm, hbase);
    k_comb<<<B*DH/256, 256, 0, stream>>>(WT, q, mcur, WC);
    k_score<<<R/TM, 256, 0, stream>>>(c, q, mcur, WC, WT, vq, vm, hbase, w1, w2, b2, sc);
    float* att = out + B*D + it*R;
    k_soft<<<B, 256, 0, stream>>>(sc, len, att);
    k_epart<<<B*NCH, 256, 0, stream>>>(c, att, len, epart);
    k_gru<<<B, 256, 0, stream>>>(wih, whh, bih, bhh, epart, mcur, out, it == 2 ? 1 : 0);
  }
}

// Round 4
// 474.446 us; speedup vs baseline: 2.7772x; 2.7772x over previous
//
#include <hip/hip_runtime.h>
#include <hip/hip_bf16.h>
#include <math.h>

#define B 8
#define S 4096
#define D 256
#define H 256
#define FEAT 1794
#define R (B*S)
#define DH (D*H)
#define NCH 64   // s-chunks for e partial reduction

typedef __bf16 bf16_t;
typedef __bf16 bf16x8 __attribute__((ext_vector_type(8)));
typedef float f32x4 __attribute__((ext_vector_type(4)));

// ---------------- ws layout ----------------
// bf16 region: WCB [B][H][D], WAQ [H][D], WAM [H][D]   -> (B+2)*DH bf16
// f32 region : vq[B*D], vm[B*D], hb[B*H], mcur[B*D], epart[NCH*B*D], sc[R]
// total ~ 2 MB

__device__ __forceinline__ float waveReduceSum(float v) {
  #pragma unroll
  for (int off = 32; off; off >>= 1) v += __shfl_xor(v, off, 64);
  return v;
}

// Once: WAQ[h][k] = w1[h][5D+k], WAM[h][k] = w1[h][6D+k]  (bf16)
__global__ void k_once(const float* __restrict__ w1,
                       bf16_t* __restrict__ WAQ, bf16_t* __restrict__ WAM) {
  int idx = blockIdx.x * 256 + threadIdx.x;   // DH
  int h = idx >> 8, k = idx & 255;
  const float* w1h = w1 + (size_t)h * FEAT;
  WAQ[idx] = (bf16_t)w1h[5*D + k];
  WAM[idx] = (bf16_t)w1h[6*D + k];
}

// Once: vq = A@q, m := q.
__global__ void k_p0(const float* __restrict__ q, const float* __restrict__ A,
                     float* __restrict__ vq, float* __restrict__ mcur) {
  int b = blockIdx.x, t = threadIdx.x;
  __shared__ float qs[D];
  qs[t] = q[b*D + t];
  __syncthreads();
  float acc = 0.f;
  for (int d = 0; d < D; d++) acc += A[t*D + d] * qs[d];
  vq[b*D + t] = acc;
  mcur[b*D + t] = qs[t];
}

// Per hop: vm = A@m, hb = b1 + q@W1q^T + m@W1m^T.
__global__ void k_pm(const float* __restrict__ A, const float* __restrict__ w1,
                     const float* __restrict__ b1, const float* __restrict__ q,
                     const float* __restrict__ mcur,
                     float* __restrict__ vm, float* __restrict__ hb) {
  int b = blockIdx.x, t = threadIdx.x;
  __shared__ float msh[D], qsh[D];
  msh[t] = mcur[b*D + t];
  qsh[t] = q[b*D + t];
  __syncthreads();
  float acc = 0.f;
  for (int d = 0; d < D; d++) acc += A[t*D + d] * msh[d];
  vm[b*D + t] = acc;
  float hbv = b1[t];
  const float* w1r = w1 + (size_t)t*FEAT;
  for (int d = 0; d < D; d++) hbv += qsh[d]*w1r[2*D + d] + msh[d]*w1r[D + d];
  hb[b*H + t] = hbv;
}

// Per hop: WCB[b][h][k] = Wc + q*Wcq + m*Wcm + vq[k]*wdq[h] + vm[k]*wdm[h]  (bf16)
__global__ void k_comb(const float* __restrict__ w1, const float* __restrict__ q,
                       const float* __restrict__ mcur,
                       const float* __restrict__ vq, const float* __restrict__ vm,
                       bf16_t* __restrict__ WCB) {
  int idx = blockIdx.x * 256 + threadIdx.x;  // B*DH
  int b = idx >> 16;
  int h = (idx >> 8) & 255;
  int k = idx & 255;
  const float* w1h = w1 + (size_t)h * FEAT;
  float v = w1h[k] + q[b*D + k]*w1h[3*D + k] + mcur[b*D + k]*w1h[4*D + k]
          + vq[b*D + k]*w1h[7*D] + vm[b*D + k]*w1h[7*D + 1];
  WCB[idx] = (bf16_t)v;
}

// MFMA score kernel: 64 rows x 256 h per block, 4 waves.
// scores[r] = sum_h tanh( [c|,|c-q|,|c-m|] @ W  + hb[h] ) * w2[h]  + b2
__global__ __launch_bounds__(256) void k_score(
    const float* __restrict__ c, const float* __restrict__ q,
    const float* __restrict__ mcur,
    const bf16_t* __restrict__ WCB, const bf16_t* __restrict__ WAQ,
    const bf16_t* __restrict__ WAM,
    const float* __restrict__ hb, const float* __restrict__ w2,
    const float* __restrict__ b2, float* __restrict__ scores) {
  const int t = threadIdx.x;
  const int lane = t & 63, wave = t >> 6;
  const int r0 = blockIdx.x * 64;
  const int b = r0 >> 12;          // S = 4096 rows per batch
  const int lrow = lane & 15;
  const int lk = (lane >> 4) * 8;
  const int n0 = wave * 64;

  f32x4 acc[4][4];
  #pragma unroll
  for (int mi = 0; mi < 4; mi++)
    #pragma unroll
    for (int ni = 0; ni < 4; ni++) acc[mi][ni] = (f32x4){0.f,0.f,0.f,0.f};

  const float* qp = q + b*D;
  const float* mp = mcur + b*D;
  const bf16_t* wc0 = WCB + (size_t)b*DH;

  for (int k0 = 0; k0 < D; k0 += 32) {
    float qv[8], mv[8];
    *(float4*)(qv)     = *(const float4*)(qp + k0 + lk);
    *(float4*)(qv + 4) = *(const float4*)(qp + k0 + lk + 4);
    *(float4*)(mv)     = *(const float4*)(mp + k0 + lk);
    *(float4*)(mv + 4) = *(const float4*)(mp + k0 + lk + 4);

    bf16x8 bc[4], ba[4], bm[4];
    #pragma unroll
    for (int ni = 0; ni < 4; ni++) {
      const int col = n0 + ni*16 + lrow;
      bc[ni] = *(const bf16x8*)(wc0 + (size_t)col*D + k0 + lk);
      ba[ni] = *(const bf16x8*)(WAQ + (size_t)col*D + k0 + lk);
      bm[ni] = *(const bf16x8*)(WAM + (size_t)col*D + k0 + lk);
    }
    #pragma unroll
    for (int mi = 0; mi < 4; mi++) {
      const float* cp = c + (size_t)(r0 + mi*16 + lrow)*D + k0 + lk;
      float cv[8];
      *(float4*)(cv)     = *(const float4*)(cp);
      *(float4*)(cv + 4) = *(const float4*)(cp + 4);
      bf16x8 ac, aq, am;
      #pragma unroll
      for (int i = 0; i < 8; i++) {
        ac[i] = (bf16_t)cv[i];
        aq[i] = (bf16_t)fabsf(cv[i] - qv[i]);
        am[i] = (bf16_t)fabsf(cv[i] - mv[i]);
      }
      #pragma unroll
      for (int ni = 0; ni < 4; ni++) {
        acc[mi][ni] = __builtin_amdgcn_mfma_f32_16x16x32_bf16(ac, bc[ni], acc[mi][ni], 0, 0, 0);
        acc[mi][ni] = __builtin_amdgcn_mfma_f32_16x16x32_bf16(aq, ba[ni], acc[mi][ni], 0, 0, 0);
        acc[mi][ni] = __builtin_amdgcn_mfma_f32_16x16x32_bf16(am, bm[ni], acc[mi][ni], 0, 0, 0);
      }
    }
  }

  // epilogue: tanh + w2-dot, reduce over h
  float hbv[4], w2v[4];
  #pragma unroll
  for (int ni = 0; ni < 4; ni++) {
    const int col = n0 + ni*16 + lrow;
    hbv[ni] = hb[b*H + col];
    w2v[ni] = w2[col];
  }
  __shared__ float red[4][64];
  #pragma unroll
  for (int mi = 0; mi < 4; mi++) {
    #pragma unroll
    for (int j = 0; j < 4; j++) {
      float ps = 0.f;
      #pragma unroll
      for (int ni = 0; ni < 4; ni++) {
        float x = acc[mi][ni][j] + hbv[ni];
        float ex = __expf(2.f * x);
        float th = 1.f - 2.f * __builtin_amdgcn_rcpf(ex + 1.f);
        ps += th * w2v[ni];
      }
      ps += __shfl_xor(ps, 1, 64);
      ps += __shfl_xor(ps, 2, 64);
      ps += __shfl_xor(ps, 4, 64);
      ps += __shfl_xor(ps, 8, 64);
      if (lrow == 0) red[wave][mi*16 + (lane >> 4)*4 + j] = ps;
    }
  }
  __syncthreads();
  if (t < 64) scores[r0 + t] = red[0][t] + red[1][t] + red[2][t] + red[3][t] + b2[0];
}

// Masked softmax over S per batch (1024 threads, 2 passes over scores).
__global__ __launch_bounds__(1024) void k_soft(const float* __restrict__ scores,
                                               const int* __restrict__ len_c,
                                               float* __restrict__ att) {
  const int b = blockIdx.x, t = threadIdx.x;
  const int len = len_c[b];
  __shared__ float rbuf[16];
  const float* sc = scores + b*S;
  float mx = -1e30f;
  for (int s = t; s < len; s += 1024) mx = fmaxf(mx, sc[s]);
  #pragma unroll
  for (int off = 32; off; off >>= 1) mx = fmaxf(mx, __shfl_xor(mx, off, 64));
  if ((t & 63) == 0) rbuf[t >> 6] = mx;
  __syncthreads();
  mx = rbuf[0];
  #pragma unroll
  for (int i = 1; i < 16; i++) mx = fmaxf(mx, rbuf[i]);
  __syncthreads();
  float sum = 0.f;
  float* ab = att + b*S;
  for (int s = t; s < S; s += 1024) {
    if (s < len) { float e = __expf(sc[s] - mx); ab[s] = e; sum += e; }
    else ab[s] = 0.f;
  }
  sum = waveReduceSum(sum);
  if ((t & 63) == 0) rbuf[t >> 6] = sum;
  __syncthreads();
  sum = 0.f;
  #pragma unroll
  for (int i = 0; i < 16; i++) sum += rbuf[i];
  const float inv = 1.f / sum;
  for (int s = t; s < len; s += 1024) ab[s] *= inv;
}

// epart[ch,b,d] = sum_{s in chunk, s<len} att[s]*c[b,s,d]
__global__ void k_epart(const float* __restrict__ c, const float* __restrict__ att,
                        const int* __restrict__ len_c, float* __restrict__ epart) {
  const int b = blockIdx.x >> 6, ch = blockIdx.x & 63;
  const int t = threadIdx.x;
  const int len = len_c[b];
  const int s0 = ch * (S / NCH);
  const int send = min(s0 + (S / NCH), len);
  float acc = 0.f;
  const float* ab = att + b*S;
  int s = s0;
  for (; s + 3 < send; s += 4) {
    float a0 = ab[s], a1 = ab[s+1], a2 = ab[s+2], a3 = ab[s+3];
    const float* cp = c + (size_t)(b*S + s)*D + t;
    acc += a0*cp[0] + a1*cp[D] + a2*cp[2*D] + a3*cp[3*D];
  }
  for (; s < send; s++) acc += ab[s] * c[(size_t)(b*S + s)*D + t];
  epart[(ch*B + b)*D + t] = acc;
}

// GRU cell: e = sum(epart), gates, update mcur (final output on last hop).
__global__ void k_gru(const float* __restrict__ wih, const float* __restrict__ whh,
                      const float* __restrict__ bih, const float* __restrict__ bhh,
                      const float* __restrict__ epart, float* __restrict__ mcur,
                      float* __restrict__ out, const int write_out) {
  const int b = blockIdx.x, t = threadIdx.x;
  __shared__ float es[D], ms[D], gis[3*D], ghs[3*D];
  float e = 0.f;
  #pragma unroll
  for (int ch = 0; ch < NCH; ch++) e += epart[(ch*B + b)*D + t];
  es[t] = e;
  ms[t] = mcur[b*D + t];
  __syncthreads();
  #pragma unroll
  for (int jj = 0; jj < 3; jj++) {
    const int j = jj*D + t;
    float gi = bih[j], gh = bhh[j];
    const float* wi = wih + (size_t)j*D;
    const float* wh = whh + (size_t)j*D;
    for (int d = 0; d < D; d++) { gi += es[d]*wi[d]; gh += ms[d]*wh[d]; }
    gis[j] = gi; ghs[j] = gh;
  }
  __syncthreads();
  float rr = 1.f / (1.f + expf(-(gis[t] + ghs[t])));
  float zz = 1.f / (1.f + expf(-(gis[D + t] + ghs[D + t])));
  float nn = tanhf(gis[2*D + t] + rr * ghs[2*D + t]);
  float mnew = (1.f - zz)*nn + zz*ms[t];
  mcur[b*D + t] = mnew;
  if (write_out) out[b*D + t] = mnew;
}

extern "C" void kernel_launch(void* const* d_in, const int* in_sizes, int n_in,
                              void* d_out, int out_size, void* d_ws, size_t ws_size,
                              hipStream_t stream) {
  const float* c   = (const float*)d_in[0];
  const float* q   = (const float*)d_in[1];
  const int*   len = (const int*)d_in[2];
  const float* A   = (const float*)d_in[3];
  const float* w1  = (const float*)d_in[4];
  const float* b1  = (const float*)d_in[5];
  const float* w2  = (const float*)d_in[6];
  const float* b2  = (const float*)d_in[7];
  const float* wih = (const float*)d_in[8];
  const float* whh = (const float*)d_in[9];
  const float* bih = (const float*)d_in[10];
  const float* bhh = (const float*)d_in[11];
  float* out = (float*)d_out;

  bf16_t* WCB = (bf16_t*)d_ws;
  bf16_t* WAQ = WCB + (size_t)B*DH;
  bf16_t* WAM = WAQ + DH;
  float* fb    = (float*)(WAM + DH);   // (B+2)*DH*2 bytes offset, 16B-aligned
  float* vq    = fb;
  float* vm    = vq + B*D;
  float* hb    = vm + B*D;
  float* mcur  = hb + B*H;
  float* epart = mcur + B*D;
  float* sc    = epart + NCH*B*D;

  k_once<<<DH/256, 256, 0, stream>>>(w1, WAQ, WAM);
  k_p0<<<B, 256, 0, stream>>>(q, A, vq, mcur);

  for (int it = 0; it < 3; ++it) {
    k_pm<<<B, 256, 0, stream>>>(A, w1, b1, q, mcur, vm, hb);
    k_comb<<<B*DH/256, 256, 0, stream>>>(w1, q, mcur, vq, vm, WCB);
    k_score<<<R/64, 256, 0, stream>>>(c, q, mcur, WCB, WAQ, WAM, hb, w2, b2, sc);
    float* att = out + B*D + it*R;
    k_soft<<<B, 1024, 0, stream>>>(sc, len, att);
    k_epart<<<B*NCH, 256, 0, stream>>>(c, att, len, epart);
    k_gru<<<B, 256, 0, stream>>>(wih, whh, bih, bhh, epart, mcur, out, it == 2 ? 1 : 0);
  }
}

// Round 5
// 269.673 us; speedup vs baseline: 4.8861x; 1.7593x over previous
//
#include <hip/hip_runtime.h>
#include <hip/hip_bf16.h>
#include <math.h>

#define B 8
#define S 4096
#define D 256
#define H 256
#define FEAT 1794
#define R (B*S)
#define DH (D*H)
#define NCH 64   // s-chunks for e partial reduction

typedef __bf16 bf16_t;
typedef __bf16 bf16x8 __attribute__((ext_vector_type(8)));
typedef float f32x4 __attribute__((ext_vector_type(4)));

__device__ __forceinline__ float waveReduceSum(float v) {
  #pragma unroll
  for (int off = 32; off; off >>= 1) v += __shfl_xor(v, off, 64);
  return v;
}

// ---------- once-per-launch kernels ----------

// WAQ[h][k] = w1[h][5D+k], WAM[h][k] = w1[h][6D+k]  (bf16)
__global__ void k_once(const float* __restrict__ w1,
                       bf16_t* __restrict__ WAQ, bf16_t* __restrict__ WAM) {
  int idx = blockIdx.x * 256 + threadIdx.x;   // DH
  int h = idx >> 8, k = idx & 255;
  const float* w1h = w1 + (size_t)h * FEAT;
  WAQ[idx] = (bf16_t)w1h[5*D + k];
  WAM[idx] = (bf16_t)w1h[6*D + k];
}

// CBF = bf16(c), AQB = bf16(|c-q|)   (PRE path only)
__global__ void k_prec(const float* __restrict__ c, const float* __restrict__ q,
                       bf16_t* __restrict__ CBF, bf16_t* __restrict__ AQB) {
  int gid = blockIdx.x * 256 + threadIdx.x;   // R*D/8
  int r = gid >> 5;
  int k0 = (gid & 31) * 8;
  int b = r >> 12;
  const float* cp = c + (size_t)r*D + k0;
  const float* qp = q + b*D + k0;
  float cv[8], qv[8];
  *(float4*)(cv)   = *(const float4*)(cp);
  *(float4*)(cv+4) = *(const float4*)(cp + 4);
  *(float4*)(qv)   = *(const float4*)(qp);
  *(float4*)(qv+4) = *(const float4*)(qp + 4);
  bf16x8 cb, ab;
  #pragma unroll
  for (int i = 0; i < 8; i++) {
    cb[i] = (bf16_t)cv[i];
    ab[i] = (bf16_t)fabsf(cv[i] - qv[i]);
  }
  *(bf16x8*)(CBF + (size_t)gid*8) = cb;
  *(bf16x8*)(AQB + (size_t)gid*8) = ab;
}

// vq[b][t] = A[t,:] . q[b,:]   — one wave per output
__global__ void k_p02(const float* __restrict__ q, const float* __restrict__ A,
                      float* __restrict__ vq) {
  const int blk = blockIdx.x;              // B*64
  const int b = blk >> 6;
  const int lane = threadIdx.x & 63, wave = threadIdx.x >> 6;
  const int t = (blk & 63)*4 + wave;
  const int l4 = lane * 4;
  float4 q4 = *(const float4*)(q + b*D + l4);
  float4 a4 = *(const float4*)(A + (size_t)t*D + l4);
  float s = a4.x*q4.x + a4.y*q4.y + a4.z*q4.z + a4.w*q4.w;
  s = waveReduceSum(s);
  if (lane == 0) vq[b*D + t] = s;
}

__global__ void k_minit(const float* __restrict__ q, float* __restrict__ m0) {
  m0[blockIdx.x*256 + threadIdx.x] = q[blockIdx.x*256 + threadIdx.x];
}

// ---------- per-hop kernels ----------

// vm[b][t] = A[t,:].m ; hb[b][t] = b1[t] + q.w1[t][2D:3D] + m.w1[t][D:2D]
__global__ void k_pm2(const float* __restrict__ A, const float* __restrict__ w1,
                      const float* __restrict__ b1, const float* __restrict__ q,
                      const float* __restrict__ min_,
                      float* __restrict__ vm, float* __restrict__ hb) {
  const int blk = blockIdx.x;              // B*64
  const int b = blk >> 6;
  const int lane = threadIdx.x & 63, wave = threadIdx.x >> 6;
  const int t = (blk & 63)*4 + wave;
  const int l4 = lane * 4;
  float4 m4 = *(const float4*)(min_ + b*D + l4);
  float4 q4 = *(const float4*)(q + b*D + l4);
  float4 a4 = *(const float4*)(A + (size_t)t*D + l4);
  const float* w1r = w1 + (size_t)t*FEAT;
  // w1 rows are only 8B-aligned (FEAT=1794) -> float2 loads
  float2 wm0 = *(const float2*)(w1r + D + l4);
  float2 wm1 = *(const float2*)(w1r + D + l4 + 2);
  float2 wq0 = *(const float2*)(w1r + 2*D + l4);
  float2 wq1 = *(const float2*)(w1r + 2*D + l4 + 2);
  float sv = a4.x*m4.x + a4.y*m4.y + a4.z*m4.z + a4.w*m4.w;
  float sh = m4.x*wm0.x + m4.y*wm0.y + m4.z*wm1.x + m4.w*wm1.y
           + q4.x*wq0.x + q4.y*wq0.y + q4.z*wq1.x + q4.w*wq1.y;
  sv = waveReduceSum(sv);
  sh = waveReduceSum(sh);
  if (lane == 0) { vm[b*D + t] = sv; hb[b*H + t] = b1[t] + sh; }
}

// WCB[b][h][k] = Wc + q*Wcq + m*Wcm + vq[k]*wdq[h] + vm[k]*wdm[h]  (bf16)
__global__ void k_comb(const float* __restrict__ w1, const float* __restrict__ q,
                       const float* __restrict__ min_,
                       const float* __restrict__ vq, const float* __restrict__ vm,
                       bf16_t* __restrict__ WCB) {
  int idx = blockIdx.x * 256 + threadIdx.x;  // B*DH
  int b = idx >> 16;
  int h = (idx >> 8) & 255;
  int k = idx & 255;
  const float* w1h = w1 + (size_t)h * FEAT;
  float v = w1h[k] + q[b*D + k]*w1h[3*D + k] + min_[b*D + k]*w1h[4*D + k]
          + vq[b*D + k]*w1h[7*D] + vm[b*D + k]*w1h[7*D + 1];
  WCB[idx] = (bf16_t)v;
}

// AMB = bf16(|c-m|)   (PRE path only, per hop)
__global__ void k_amb(const float* __restrict__ c, const float* __restrict__ min_,
                      bf16_t* __restrict__ AMB) {
  int gid = blockIdx.x * 256 + threadIdx.x;   // R*D/8
  int r = gid >> 5;
  int k0 = (gid & 31) * 8;
  int b = r >> 12;
  const float* cp = c + (size_t)r*D + k0;
  const float* mp = min_ + b*D + k0;
  float cv[8], mv[8];
  *(float4*)(cv)   = *(const float4*)(cp);
  *(float4*)(cv+4) = *(const float4*)(cp + 4);
  *(float4*)(mv)   = *(const float4*)(mp);
  *(float4*)(mv+4) = *(const float4*)(mp + 4);
  bf16x8 ab;
  #pragma unroll
  for (int i = 0; i < 8; i++) ab[i] = (bf16_t)fabsf(cv[i] - mv[i]);
  *(bf16x8*)(AMB + (size_t)gid*8) = ab;
}

// MFMA score, PRE path: all operands preconverted bf16; zero cvt VALU.
__global__ __launch_bounds__(256) void k_score_pre(
    const bf16_t* __restrict__ CBF, const bf16_t* __restrict__ AQB,
    const bf16_t* __restrict__ AMB,
    const bf16_t* __restrict__ WCB, const bf16_t* __restrict__ WAQ,
    const bf16_t* __restrict__ WAM,
    const float* __restrict__ hb, const float* __restrict__ w2,
    const float* __restrict__ b2, float* __restrict__ scores) {
  const int t = threadIdx.x;
  const int lane = t & 63, wave = t >> 6;
  const int r0 = blockIdx.x * 64;
  const int b = r0 >> 12;
  const int lrow = lane & 15;
  const int lk = (lane >> 4) * 8;
  const int n0 = wave * 64;

  f32x4 acc[4][4];
  #pragma unroll
  for (int mi = 0; mi < 4; mi++)
    #pragma unroll
    for (int ni = 0; ni < 4; ni++) acc[mi][ni] = (f32x4){0.f,0.f,0.f,0.f};

  const bf16_t* wc0 = WCB + (size_t)b*DH;

  for (int k0 = 0; k0 < D; k0 += 32) {
    bf16x8 bc[4], ba[4], bm[4];
    #pragma unroll
    for (int ni = 0; ni < 4; ni++) {
      const size_t off = (size_t)(n0 + ni*16 + lrow)*D + k0 + lk;
      bc[ni] = *(const bf16x8*)(wc0 + off);
      ba[ni] = *(const bf16x8*)(WAQ + off);
      bm[ni] = *(const bf16x8*)(WAM + off);
    }
    #pragma unroll
    for (int mi = 0; mi < 4; mi++) {
      const size_t aoff = (size_t)(r0 + mi*16 + lrow)*D + k0 + lk;
      bf16x8 ac = *(const bf16x8*)(CBF + aoff);
      bf16x8 aq = *(const bf16x8*)(AQB + aoff);
      bf16x8 am = *(const bf16x8*)(AMB + aoff);
      #pragma unroll
      for (int ni = 0; ni < 4; ni++) {
        acc[mi][ni] = __builtin_amdgcn_mfma_f32_16x16x32_bf16(ac, bc[ni], acc[mi][ni], 0, 0, 0);
        acc[mi][ni] = __builtin_amdgcn_mfma_f32_16x16x32_bf16(aq, ba[ni], acc[mi][ni], 0, 0, 0);
        acc[mi][ni] = __builtin_amdgcn_mfma_f32_16x16x32_bf16(am, bm[ni], acc[mi][ni], 0, 0, 0);
      }
    }
  }

  float hbv[4], w2v[4];
  #pragma unroll
  for (int ni = 0; ni < 4; ni++) {
    const int col = n0 + ni*16 + lrow;
    hbv[ni] = hb[b*H + col];
    w2v[ni] = w2[col];
  }
  __shared__ float red[4][64];
  #pragma unroll
  for (int mi = 0; mi < 4; mi++) {
    #pragma unroll
    for (int j = 0; j < 4; j++) {
      float ps = 0.f;
      #pragma unroll
      for (int ni = 0; ni < 4; ni++) {
        float x = acc[mi][ni][j] + hbv[ni];
        float ex = __expf(2.f * x);
        float th = 1.f - 2.f * __builtin_amdgcn_rcpf(ex + 1.f);
        ps += th * w2v[ni];
      }
      ps += __shfl_xor(ps, 1, 64);
      ps += __shfl_xor(ps, 2, 64);
      ps += __shfl_xor(ps, 4, 64);
      ps += __shfl_xor(ps, 8, 64);
      if (lrow == 0) red[wave][mi*16 + (lane >> 4)*4 + j] = ps;
    }
  }
  __syncthreads();
  if (t < 64) scores[r0 + t] = red[0][t] + red[1][t] + red[2][t] + red[3][t] + b2[0];
}

// MFMA score, fallback path (round-4, in-kernel conversion).
__global__ __launch_bounds__(256) void k_score_old(
    const float* __restrict__ c, const float* __restrict__ q,
    const float* __restrict__ mcur,
    const bf16_t* __restrict__ WCB, const bf16_t* __restrict__ WAQ,
    const bf16_t* __restrict__ WAM,
    const float* __restrict__ hb, const float* __restrict__ w2,
    const float* __restrict__ b2, float* __restrict__ scores) {
  const int t = threadIdx.x;
  const int lane = t & 63, wave = t >> 6;
  const int r0 = blockIdx.x * 64;
  const int b = r0 >> 12;
  const int lrow = lane & 15;
  const int lk = (lane >> 4) * 8;
  const int n0 = wave * 64;

  f32x4 acc[4][4];
  #pragma unroll
  for (int mi = 0; mi < 4; mi++)
    #pragma unroll
    for (int ni = 0; ni < 4; ni++) acc[mi][ni] = (f32x4){0.f,0.f,0.f,0.f};

  const float* qp = q + b*D;
  const float* mp = mcur + b*D;
  const bf16_t* wc0 = WCB + (size_t)b*DH;

  for (int k0 = 0; k0 < D; k0 += 32) {
    float qv[8], mv[8];
    *(float4*)(qv)     = *(const float4*)(qp + k0 + lk);
    *(float4*)(qv + 4) = *(const float4*)(qp + k0 + lk + 4);
    *(float4*)(mv)     = *(const float4*)(mp + k0 + lk);
    *(float4*)(mv + 4) = *(const float4*)(mp + k0 + lk + 4);
    bf16x8 bc[4], ba[4], bm[4];
    #pragma unroll
    for (int ni = 0; ni < 4; ni++) {
      const size_t off = (size_t)(n0 + ni*16 + lrow)*D + k0 + lk;
      bc[ni] = *(const bf16x8*)(wc0 + off);
      ba[ni] = *(const bf16x8*)(WAQ + off);
      bm[ni] = *(const bf16x8*)(WAM + off);
    }
    #pragma unroll
    for (int mi = 0; mi < 4; mi++) {
      const float* cp = c + (size_t)(r0 + mi*16 + lrow)*D + k0 + lk;
      float cv[8];
      *(float4*)(cv)     = *(const float4*)(cp);
      *(float4*)(cv + 4) = *(const float4*)(cp + 4);
      bf16x8 ac, aq, am;
      #pragma unroll
      for (int i = 0; i < 8; i++) {
        ac[i] = (bf16_t)cv[i];
        aq[i] = (bf16_t)fabsf(cv[i] - qv[i]);
        am[i] = (bf16_t)fabsf(cv[i] - mv[i]);
      }
      #pragma unroll
      for (int ni = 0; ni < 4; ni++) {
        acc[mi][ni] = __builtin_amdgcn_mfma_f32_16x16x32_bf16(ac, bc[ni], acc[mi][ni], 0, 0, 0);
        acc[mi][ni] = __builtin_amdgcn_mfma_f32_16x16x32_bf16(aq, ba[ni], acc[mi][ni], 0, 0, 0);
        acc[mi][ni] = __builtin_amdgcn_mfma_f32_16x16x32_bf16(am, bm[ni], acc[mi][ni], 0, 0, 0);
      }
    }
  }

  float hbv[4], w2v[4];
  #pragma unroll
  for (int ni = 0; ni < 4; ni++) {
    const int col = n0 + ni*16 + lrow;
    hbv[ni] = hb[b*H + col];
    w2v[ni] = w2[col];
  }
  __shared__ float red[4][64];
  #pragma unroll
  for (int mi = 0; mi < 4; mi++) {
    #pragma unroll
    for (int j = 0; j < 4; j++) {
      float ps = 0.f;
      #pragma unroll
      for (int ni = 0; ni < 4; ni++) {
        float x = acc[mi][ni][j] + hbv[ni];
        float ex = __expf(2.f * x);
        float th = 1.f - 2.f * __builtin_amdgcn_rcpf(ex + 1.f);
        ps += th * w2v[ni];
      }
      ps += __shfl_xor(ps, 1, 64);
      ps += __shfl_xor(ps, 2, 64);
      ps += __shfl_xor(ps, 4, 64);
      ps += __shfl_xor(ps, 8, 64);
      if (lrow == 0) red[wave][mi*16 + (lane >> 4)*4 + j] = ps;
    }
  }
  __syncthreads();
  if (t < 64) scores[r0 + t] = red[0][t] + red[1][t] + red[2][t] + red[3][t] + b2[0];
}

// Masked softmax over S per batch.
__global__ __launch_bounds__(1024) void k_soft(const float* __restrict__ scores,
                                               const int* __restrict__ len_c,
                                               float* __restrict__ att) {
  const int b = blockIdx.x, t = threadIdx.x;
  const int len = len_c[b];
  __shared__ float rbuf[16];
  const float* sc = scores + b*S;
  float mx = -1e30f;
  for (int s = t; s < len; s += 1024) mx = fmaxf(mx, sc[s]);
  #pragma unroll
  for (int off = 32; off; off >>= 1) mx = fmaxf(mx, __shfl_xor(mx, off, 64));
  if ((t & 63) == 0) rbuf[t >> 6] = mx;
  __syncthreads();
  mx = rbuf[0];
  #pragma unroll
  for (int i = 1; i < 16; i++) mx = fmaxf(mx, rbuf[i]);
  __syncthreads();
  float sum = 0.f;
  float* ab = att + b*S;
  for (int s = t; s < S; s += 1024) {
    if (s < len) { float e = __expf(sc[s] - mx); ab[s] = e; sum += e; }
    else ab[s] = 0.f;
  }
  sum = waveReduceSum(sum);
  if ((t & 63) == 0) rbuf[t >> 6] = sum;
  __syncthreads();
  sum = 0.f;
  #pragma unroll
  for (int i = 0; i < 16; i++) sum += rbuf[i];
  const float inv = 1.f / sum;
  for (int s = t; s < len; s += 1024) ab[s] *= inv;
}

// epart from bf16 c (PRE) — lanes read consecutive 2B: coalesced.
__global__ void k_epart_bf(const bf16_t* __restrict__ CBF, const float* __restrict__ att,
                           const int* __restrict__ len_c, float* __restrict__ epart) {
  const int b = blockIdx.x >> 6, ch = blockIdx.x & 63;
  const int t = threadIdx.x;
  const int len = len_c[b];
  const int s0 = ch * (S / NCH);
  const int send = min(s0 + (S / NCH), len);
  float acc = 0.f;
  const float* ab = att + b*S;
  int s = s0;
  for (; s + 3 < send; s += 4) {
    float a0 = ab[s], a1 = ab[s+1], a2 = ab[s+2], a3 = ab[s+3];
    const bf16_t* cp = CBF + (size_t)(b*S + s)*D + t;
    acc += a0*(float)cp[0] + a1*(float)cp[D] + a2*(float)cp[2*D] + a3*(float)cp[3*D];
  }
  for (; s < send; s++) acc += ab[s] * (float)CBF[(size_t)(b*S + s)*D + t];
  epart[(ch*B + b)*D + t] = acc;
}

// epart from f32 c (fallback).
__global__ void k_epart_f32(const float* __restrict__ c, const float* __restrict__ att,
                            const int* __restrict__ len_c, float* __restrict__ epart) {
  const int b = blockIdx.x >> 6, ch = blockIdx.x & 63;
  const int t = threadIdx.x;
  const int len = len_c[b];
  const int s0 = ch * (S / NCH);
  const int send = min(s0 + (S / NCH), len);
  float acc = 0.f;
  const float* ab = att + b*S;
  int s = s0;
  for (; s + 3 < send; s += 4) {
    float a0 = ab[s], a1 = ab[s+1], a2 = ab[s+2], a3 = ab[s+3];
    const float* cp = c + (size_t)(b*S + s)*D + t;
    acc += a0*cp[0] + a1*cp[D] + a2*cp[2*D] + a3*cp[3*D];
  }
  for (; s < send; s++) acc += ab[s] * c[(size_t)(b*S + s)*D + t];
  epart[(ch*B + b)*D + t] = acc;
}

// GRU: es = sum(epart); 6 coalesced wave-dots per t; gates elementwise.
// Reads min_, writes mout (ping-pong), optional final out.
__global__ __launch_bounds__(256) void k_gru2(
    const float* __restrict__ wih, const float* __restrict__ whh,
    const float* __restrict__ bih, const float* __restrict__ bhh,
    const float* __restrict__ epart, const float* __restrict__ min_,
    float* __restrict__ mout, float* __restrict__ out, const int write_out) {
  const int blk = blockIdx.x;         // B*16
  const int b = blk >> 4;
  const int t0 = (blk & 15) << 4;
  const int t = threadIdx.x;
  const int lane = t & 63, wave = t >> 6;
  __shared__ float es[D], ms[D];
  float e = 0.f;
  #pragma unroll
  for (int ch = 0; ch < NCH; ch++) e += epart[(ch*B + b)*D + t];
  es[t] = e;
  ms[t] = min_[b*D + t];
  __syncthreads();
  const int l4 = lane * 4;
  float4 e4 = *(const float4*)(es + l4);
  float4 m4 = *(const float4*)(ms + l4);
  #pragma unroll
  for (int tl = 0; tl < 4; tl++) {
    const int tt = t0 + wave*4 + tl;
    float g[6];
    #pragma unroll
    for (int gg = 0; gg < 3; gg++) {
      const int j = gg*D + tt;
      const float4 wi4 = *(const float4*)(wih + (size_t)j*D + l4);
      const float4 wh4 = *(const float4*)(whh + (size_t)j*D + l4);
      float gi = e4.x*wi4.x + e4.y*wi4.y + e4.z*wi4.z + e4.w*wi4.w;
      float gh = m4.x*wh4.x + m4.y*wh4.y + m4.z*wh4.z + m4.w*wh4.w;
      g[gg]   = waveReduceSum(gi);
      g[3+gg] = waveReduceSum(gh);
    }
    if (lane == 0) {
      const int j0 = tt, j1 = D + tt, j2 = 2*D + tt;
      float gir = g[0] + bih[j0], giz = g[1] + bih[j1], gin = g[2] + bih[j2];
      float ghr = g[3] + bhh[j0], ghz = g[4] + bhh[j1], ghn = g[5] + bhh[j2];
      float rr = 1.f / (1.f + __expf(-(gir + ghr)));
      float zz = 1.f / (1.f + __expf(-(giz + ghz)));
      float nn = tanhf(gin + rr * ghn);
      float mn = (1.f - zz)*nn + zz*ms[tt];
      mout[b*D + tt] = mn;
      if (write_out) out[b*D + tt] = mn;
    }
  }
}

extern "C" void kernel_launch(void* const* d_in, const int* in_sizes, int n_in,
                              void* d_out, int out_size, void* d_ws, size_t ws_size,
                              hipStream_t stream) {
  const float* c   = (const float*)d_in[0];
  const float* q   = (const float*)d_in[1];
  const int*   len = (const int*)d_in[2];
  const float* A   = (const float*)d_in[3];
  const float* w1  = (const float*)d_in[4];
  const float* b1  = (const float*)d_in[5];
  const float* w2  = (const float*)d_in[6];
  const float* b2  = (const float*)d_in[7];
  const float* wih = (const float*)d_in[8];
  const float* whh = (const float*)d_in[9];
  const float* bih = (const float*)d_in[10];
  const float* bhh = (const float*)d_in[11];
  float* out = (float*)d_out;

  const size_t F32_CNT = (size_t)4*B*D + B*H + (size_t)NCH*B*D + R;
  const size_t BF_SMALL = (size_t)(B + 2)*DH;
  const size_t BF_PRE = BF_SMALL + 3*(size_t)R*D;
  const size_t NEED_PRE = BF_PRE*2 + F32_CNT*4;
  const bool pre = ws_size >= NEED_PRE;

  bf16_t* WCB = (bf16_t*)d_ws;
  bf16_t* WAQ = WCB + (size_t)B*DH;
  bf16_t* WAM = WAQ + DH;
  bf16_t* CBF = WAM + DH;
  bf16_t* AQB = CBF + (size_t)R*D;
  bf16_t* AMB = AQB + (size_t)R*D;
  float* fb = (float*)((bf16_t*)d_ws + (pre ? BF_PRE : BF_SMALL));
  float* vq    = fb;
  float* vm    = vq + B*D;
  float* hb    = vm + B*D;
  float* m0    = hb + B*H;
  float* m1    = m0 + B*D;
  float* epart = m1 + B*D;
  float* sc    = epart + (size_t)NCH*B*D;

  k_once<<<DH/256, 256, 0, stream>>>(w1, WAQ, WAM);
  if (pre) k_prec<<<R*D/2048, 256, 0, stream>>>(c, q, CBF, AQB);
  k_p02<<<B*64, 256, 0, stream>>>(q, A, vq);
  k_minit<<<B, 256, 0, stream>>>(q, m0);

  for (int it = 0; it < 3; ++it) {
    float* min_ = (it & 1) ? m1 : m0;
    float* mout = (it & 1) ? m0 : m1;
    k_pm2<<<B*64, 256, 0, stream>>>(A, w1, b1, q, min_, vm, hb);
    k_comb<<<B*DH/256, 256, 0, stream>>>(w1, q, min_, vq, vm, WCB);
    if (pre) {
      k_amb<<<R*D/2048, 256, 0, stream>>>(c, min_, AMB);
      k_score_pre<<<R/64, 256, 0, stream>>>(CBF, AQB, AMB, WCB, WAQ, WAM, hb, w2, b2, sc);
    } else {
      k_score_old<<<R/64, 256, 0, stream>>>(c, q, min_, WCB, WAQ, WAM, hb, w2, b2, sc);
    }
    float* att = out + B*D + (size_t)it*R;
    k_soft<<<B, 1024, 0, stream>>>(sc, len, att);
    if (pre) k_epart_bf<<<B*NCH, 256, 0, stream>>>(CBF, att, len, epart);
    else     k_epart_f32<<<B*NCH, 256, 0, stream>>>(c, att, len, epart);
    k_gru2<<<B*16, 256, 0, stream>>>(wih, whh, bih, bhh, epart, min_, mout, out, it == 2 ? 1 : 0);
  }
}

// Round 6
// 210.349 us; speedup vs baseline: 6.2641x; 1.2820x over previous
//
#include <hip/hip_runtime.h>
#include <hip/hip_bf16.h>
#include <math.h>
#include <stdint.h>

#define B 8
#define S 4096
#define D 256
#define H 256
#define FEAT 1794
#define R (B*S)
#define DH (D*H)
#define NCH 64   // s-chunks for e partial reduction

typedef __bf16 bf16_t;
typedef __bf16 bf16x8 __attribute__((ext_vector_type(8)));
typedef float f32x4 __attribute__((ext_vector_type(4)));

#define GLOAD16(gp, lp) __builtin_amdgcn_global_load_lds( \
  (const __attribute__((address_space(1))) void*)(gp), \
  (__attribute__((address_space(3))) void*)(lp), 16, 0, 0)

__device__ __forceinline__ float waveReduceSum(float v) {
  #pragma unroll
  for (int off = 32; off; off >>= 1) v += __shfl_xor(v, off, 64);
  return v;
}

// ---------- once-per-launch kernels ----------

// WAQ[h][k] = w1[h][5D+k], WAM[h][k] = w1[h][6D+k]  (bf16)
__global__ void k_once(const float* __restrict__ w1,
                       bf16_t* __restrict__ WAQ, bf16_t* __restrict__ WAM) {
  int idx = blockIdx.x * 256 + threadIdx.x;   // DH
  int h = idx >> 8, k = idx & 255;
  const float* w1h = w1 + (size_t)h * FEAT;
  WAQ[idx] = (bf16_t)w1h[5*D + k];
  WAM[idx] = (bf16_t)w1h[6*D + k];
}

// CBF = bf16(c), AQB = bf16(|c-q|)
__global__ void k_prec(const float* __restrict__ c, const float* __restrict__ q,
                       bf16_t* __restrict__ CBF, bf16_t* __restrict__ AQB) {
  int gid = blockIdx.x * 256 + threadIdx.x;   // R*D/8
  int r = gid >> 5;
  int k0 = (gid & 31) * 8;
  int b = r >> 12;
  const float* cp = c + (size_t)r*D + k0;
  const float* qp = q + b*D + k0;
  float cv[8], qv[8];
  *(float4*)(cv)   = *(const float4*)(cp);
  *(float4*)(cv+4) = *(const float4*)(cp + 4);
  *(float4*)(qv)   = *(const float4*)(qp);
  *(float4*)(qv+4) = *(const float4*)(qp + 4);
  bf16x8 cb, ab;
  #pragma unroll
  for (int i = 0; i < 8; i++) {
    cb[i] = (bf16_t)cv[i];
    ab[i] = (bf16_t)fabsf(cv[i] - qv[i]);
  }
  *(bf16x8*)(CBF + (size_t)gid*8) = cb;
  *(bf16x8*)(AQB + (size_t)gid*8) = ab;
}

// vq[b][t] = A[t,:] . q[b,:]   — one wave per output
__global__ void k_p02(const float* __restrict__ q, const float* __restrict__ A,
                      float* __restrict__ vq) {
  const int blk = blockIdx.x;              // B*64
  const int b = blk >> 6;
  const int lane = threadIdx.x & 63, wave = threadIdx.x >> 6;
  const int t = (blk & 63)*4 + wave;
  const int l4 = lane * 4;
  float4 q4 = *(const float4*)(q + b*D + l4);
  float4 a4 = *(const float4*)(A + (size_t)t*D + l4);
  float s = a4.x*q4.x + a4.y*q4.y + a4.z*q4.z + a4.w*q4.w;
  s = waveReduceSum(s);
  if (lane == 0) vq[b*D + t] = s;
}

__global__ void k_minit(const float* __restrict__ q, float* __restrict__ m0) {
  m0[blockIdx.x*256 + threadIdx.x] = q[blockIdx.x*256 + threadIdx.x];
}

// ---------- per-hop kernels ----------

// vm[b][t] = A[t,:].m ; hb[b][t] = b1[t] + q.w1[t][2D:3D] + m.w1[t][D:2D]
__global__ void k_pm2(const float* __restrict__ A, const float* __restrict__ w1,
                      const float* __restrict__ b1, const float* __restrict__ q,
                      const float* __restrict__ min_,
                      float* __restrict__ vm, float* __restrict__ hb) {
  const int blk = blockIdx.x;              // B*64
  const int b = blk >> 6;
  const int lane = threadIdx.x & 63, wave = threadIdx.x >> 6;
  const int t = (blk & 63)*4 + wave;
  const int l4 = lane * 4;
  float4 m4 = *(const float4*)(min_ + b*D + l4);
  float4 q4 = *(const float4*)(q + b*D + l4);
  float4 a4 = *(const float4*)(A + (size_t)t*D + l4);
  const float* w1r = w1 + (size_t)t*FEAT;
  float2 wm0 = *(const float2*)(w1r + D + l4);
  float2 wm1 = *(const float2*)(w1r + D + l4 + 2);
  float2 wq0 = *(const float2*)(w1r + 2*D + l4);
  float2 wq1 = *(const float2*)(w1r + 2*D + l4 + 2);
  float sv = a4.x*m4.x + a4.y*m4.y + a4.z*m4.z + a4.w*m4.w;
  float sh = m4.x*wm0.x + m4.y*wm0.y + m4.z*wm1.x + m4.w*wm1.y
           + q4.x*wq0.x + q4.y*wq0.y + q4.z*wq1.x + q4.w*wq1.y;
  sv = waveReduceSum(sv);
  sh = waveReduceSum(sh);
  if (lane == 0) { vm[b*D + t] = sv; hb[b*H + t] = b1[t] + sh; }
}

// WCB[b][h][k] = Wc + q*Wcq + m*Wcm + vq[k]*wdq[h] + vm[k]*wdm[h]  (bf16)
__global__ void k_comb(const float* __restrict__ w1, const float* __restrict__ q,
                       const float* __restrict__ min_,
                       const float* __restrict__ vq, const float* __restrict__ vm,
                       bf16_t* __restrict__ WCB) {
  int idx = blockIdx.x * 256 + threadIdx.x;  // B*DH
  int b = idx >> 16;
  int h = (idx >> 8) & 255;
  int k = idx & 255;
  const float* w1h = w1 + (size_t)h * FEAT;
  float v = w1h[k] + q[b*D + k]*w1h[3*D + k] + min_[b*D + k]*w1h[4*D + k]
          + vq[b*D + k]*w1h[7*D] + vm[b*D + k]*w1h[7*D + 1];
  WCB[idx] = (bf16_t)v;
}

// AMB = bf16(|c-m|)   (per hop)
__global__ void k_amb(const float* __restrict__ c, const float* __restrict__ min_,
                      bf16_t* __restrict__ AMB) {
  int gid = blockIdx.x * 256 + threadIdx.x;   // R*D/8
  int r = gid >> 5;
  int k0 = (gid & 31) * 8;
  int b = r >> 12;
  const float* cp = c + (size_t)r*D + k0;
  const float* mp = min_ + b*D + k0;
  float cv[8], mv[8];
  *(float4*)(cv)   = *(const float4*)(cp);
  *(float4*)(cv+4) = *(const float4*)(cp + 4);
  *(float4*)(mv)   = *(const float4*)(mp);
  *(float4*)(mv+4) = *(const float4*)(mp + 4);
  bf16x8 ab;
  #pragma unroll
  for (int i = 0; i < 8; i++) ab[i] = (bf16_t)fabsf(cv[i] - mv[i]);
  *(bf16x8*)(AMB + (size_t)gid*8) = ab;
}

// MFMA score v3: LDS-staged A (global_load_lds, XOR-swizzled), reg-dbuf B.
// Block: 64 rows x 256 cols, 4 waves. K = 256 in 4 chunks of 64 (2 k-steps each).
// LDS A buffer: dbuf d in {0,1}: base d*24576; stream s: +s*8192;
// row r (0..63): +r*128; physical 16B slot p: +p*16, p = logical ^ (r&7).
__global__ __launch_bounds__(256) void k_score3(
    const bf16_t* __restrict__ CBF, const bf16_t* __restrict__ AQB,
    const bf16_t* __restrict__ AMB,
    const bf16_t* __restrict__ WCB, const bf16_t* __restrict__ WAQ,
    const bf16_t* __restrict__ WAM,
    const float* __restrict__ hb, const float* __restrict__ w2,
    const float* __restrict__ b2, float* __restrict__ scores) {
  __shared__ char smem[49152];
  __shared__ float red[4][64];
  const int t = threadIdx.x;
  const int lane = t & 63, wave = t >> 6;
  const int r0 = blockIdx.x * 64;
  const int b = r0 >> 12;
  const int lrow = lane & 15;
  const int lk = (lane >> 4) * 8;
  const int n0 = wave * 64;

  const char* cC = (const char*)CBF;
  const char* cQ = (const char*)AQB;
  const char* cM = (const char*)AMB;
  const bf16_t* bptrC = WCB + (size_t)b*DH;
  const bf16_t* bptrQ = WAQ;
  const bf16_t* bptrM = WAM;

  // per-lane swizzled global offset within one 1KB issue region (8 rows x 128B)
  const int g_off = ((lane >> 3) << 9) + ((((lane & 7) ^ (lane >> 3))) << 4);
  const size_t rowbytes0 = (size_t)r0 << 9;   // r0 * 512B (D bf16 per row)
  const int wave6 = wave * 6;

  f32x4 acc[4][4];
  #pragma unroll
  for (int mi = 0; mi < 4; mi++)
    #pragma unroll
    for (int ni = 0; ni < 4; ni++) acc[mi][ni] = (f32x4){0.f,0.f,0.f,0.f};

  bf16x8 breg[2][12];
  // B load for k-step ks into breg[ks&1]
  #define LOADB(ks) { \
    const int kelem = (ks)*32 + lk; \
    _Pragma("unroll") \
    for (int ni = 0; ni < 4; ni++) { \
      const size_t co = (size_t)(n0 + ni*16 + lrow) * D + kelem; \
      breg[(ks)&1][ni*3+0] = *(const bf16x8*)(bptrC + co); \
      breg[(ks)&1][ni*3+1] = *(const bf16x8*)(bptrQ + co); \
      breg[(ks)&1][ni*3+2] = *(const bf16x8*)(bptrM + co); \
    } }

  // stage chunk ch (k bytes ch*128) into dbuf d: 24 issues, 6 per wave
  #define STAGE(ch, d) { \
    const int kbyte = (ch) << 7; \
    _Pragma("unroll") \
    for (int j = 0; j < 6; j++) { \
      const int idx = wave6 + j; \
      const int s_ = idx >> 3; \
      const int r8 = (idx & 7) << 3; \
      const char* gsrc = (s_ == 0 ? cC : (s_ == 1 ? cQ : cM)) \
                       + rowbytes0 + ((size_t)r8 << 9) + kbyte + g_off; \
      GLOAD16(gsrc, smem + (d)*24576 + idx*1024); \
    } }

  LOADB(0);
  STAGE(0, 0);
  __syncthreads();

  #pragma unroll
  for (int ch = 0; ch < 4; ch++) {
    if (ch < 3) STAGE(ch + 1, (ch + 1) & 1);
    #pragma unroll
    for (int kk = 0; kk < 2; kk++) {
      const int ks = ch*2 + kk;
      if (ks < 7) LOADB(ks + 1);
      // physical slot for this k-step: logical (kk*4 + lane>>4) ^ (lane&7)
      const int p = ((kk << 2) + (lane >> 4)) ^ (lane & 7);
      const char* lb = smem + (ch & 1)*24576;
      #pragma unroll
      for (int mi = 0; mi < 4; mi++) {
        const int ro = (mi*16 + lrow)*128 + p*16;
        bf16x8 ac = *(const bf16x8*)(lb + ro);
        bf16x8 aq = *(const bf16x8*)(lb + 8192 + ro);
        bf16x8 am = *(const bf16x8*)(lb + 16384 + ro);
        #pragma unroll
        for (int ni = 0; ni < 4; ni++) {
          acc[mi][ni] = __builtin_amdgcn_mfma_f32_16x16x32_bf16(ac, breg[ks&1][ni*3+0], acc[mi][ni], 0, 0, 0);
          acc[mi][ni] = __builtin_amdgcn_mfma_f32_16x16x32_bf16(aq, breg[ks&1][ni*3+1], acc[mi][ni], 0, 0, 0);
          acc[mi][ni] = __builtin_amdgcn_mfma_f32_16x16x32_bf16(am, breg[ks&1][ni*3+2], acc[mi][ni], 0, 0, 0);
        }
      }
    }
    __syncthreads();
  }

  // epilogue: tanh + w2-dot, reduce over h (verified layout from round 5)
  float hbv[4], w2v[4];
  #pragma unroll
  for (int ni = 0; ni < 4; ni++) {
    const int col = n0 + ni*16 + lrow;
    hbv[ni] = hb[b*H + col];
    w2v[ni] = w2[col];
  }
  #pragma unroll
  for (int mi = 0; mi < 4; mi++) {
    #pragma unroll
    for (int j = 0; j < 4; j++) {
      float ps = 0.f;
      #pragma unroll
      for (int ni = 0; ni < 4; ni++) {
        float x = acc[mi][ni][j] + hbv[ni];
        float ex = __expf(2.f * x);
        float th = 1.f - 2.f * __builtin_amdgcn_rcpf(ex + 1.f);
        ps += th * w2v[ni];
      }
      ps += __shfl_xor(ps, 1, 64);
      ps += __shfl_xor(ps, 2, 64);
      ps += __shfl_xor(ps, 4, 64);
      ps += __shfl_xor(ps, 8, 64);
      if (lrow == 0) red[wave][mi*16 + (lane >> 4)*4 + j] = ps;
    }
  }
  __syncthreads();
  if (t < 64) scores[r0 + t] = red[0][t] + red[1][t] + red[2][t] + red[3][t] + b2[0];
}

// Masked softmax over S per batch.
__global__ __launch_bounds__(1024) void k_soft(const float* __restrict__ scores,
                                               const int* __restrict__ len_c,
                                               float* __restrict__ att) {
  const int b = blockIdx.x, t = threadIdx.x;
  const int len = len_c[b];
  __shared__ float rbuf[16];
  const float* sc = scores + b*S;
  float mx = -1e30f;
  for (int s = t; s < len; s += 1024) mx = fmaxf(mx, sc[s]);
  #pragma unroll
  for (int off = 32; off; off >>= 1) mx = fmaxf(mx, __shfl_xor(mx, off, 64));
  if ((t & 63) == 0) rbuf[t >> 6] = mx;
  __syncthreads();
  mx = rbuf[0];
  #pragma unroll
  for (int i = 1; i < 16; i++) mx = fmaxf(mx, rbuf[i]);
  __syncthreads();
  float sum = 0.f;
  float* ab = att + b*S;
  for (int s = t; s < S; s += 1024) {
    if (s < len) { float e = __expf(sc[s] - mx); ab[s] = e; sum += e; }
    else ab[s] = 0.f;
  }
  sum = waveReduceSum(sum);
  if ((t & 63) == 0) rbuf[t >> 6] = sum;
  __syncthreads();
  sum = 0.f;
  #pragma unroll
  for (int i = 0; i < 16; i++) sum += rbuf[i];
  const float inv = 1.f / sum;
  for (int s = t; s < len; s += 1024) ab[s] *= inv;
}

// epart from bf16 c — lanes read consecutive 2B: coalesced.
__global__ void k_epart_bf(const bf16_t* __restrict__ CBF, const float* __restrict__ att,
                           const int* __restrict__ len_c, float* __restrict__ epart) {
  const int b = blockIdx.x >> 6, ch = blockIdx.x & 63;
  const int t = threadIdx.x;
  const int len = len_c[b];
  const int s0 = ch * (S / NCH);
  const int send = min(s0 + (S / NCH), len);
  float acc = 0.f;
  const float* ab = att + b*S;
  int s = s0;
  for (; s + 3 < send; s += 4) {
    float a0 = ab[s], a1 = ab[s+1], a2 = ab[s+2], a3 = ab[s+3];
    const bf16_t* cp = CBF + (size_t)(b*S + s)*D + t;
    acc += a0*(float)cp[0] + a1*(float)cp[D] + a2*(float)cp[2*D] + a3*(float)cp[3*D];
  }
  for (; s < send; s++) acc += ab[s] * (float)CBF[(size_t)(b*S + s)*D + t];
  epart[(ch*B + b)*D + t] = acc;
}

// GRU: es = sum(epart); 6 coalesced wave-dots per t; gates elementwise.
__global__ __launch_bounds__(256) void k_gru2(
    const float* __restrict__ wih, const float* __restrict__ whh,
    const float* __restrict__ bih, const float* __restrict__ bhh,
    const float* __restrict__ epart, const float* __restrict__ min_,
    float* __restrict__ mout, float* __restrict__ out, const int write_out) {
  const int blk = blockIdx.x;         // B*16
  const int b = blk >> 4;
  const int t0 = (blk & 15) << 4;
  const int t = threadIdx.x;
  const int lane = t & 63, wave = t >> 6;
  __shared__ float es[D], ms[D];
  float e = 0.f;
  #pragma unroll
  for (int ch = 0; ch < NCH; ch++) e += epart[(ch*B + b)*D + t];
  es[t] = e;
  ms[t] = min_[b*D + t];
  __syncthreads();
  const int l4 = lane * 4;
  float4 e4 = *(const float4*)(es + l4);
  float4 m4 = *(const float4*)(ms + l4);
  #pragma unroll
  for (int tl = 0; tl < 4; tl++) {
    const int tt = t0 + wave*4 + tl;
    float g[6];
    #pragma unroll
    for (int gg = 0; gg < 3; gg++) {
      const int j = gg*D + tt;
      const float4 wi4 = *(const float4*)(wih + (size_t)j*D + l4);
      const float4 wh4 = *(const float4*)(whh + (size_t)j*D + l4);
      float gi = e4.x*wi4.x + e4.y*wi4.y + e4.z*wi4.z + e4.w*wi4.w;
      float gh = m4.x*wh4.x + m4.y*wh4.y + m4.z*wh4.z + m4.w*wh4.w;
      g[gg]   = waveReduceSum(gi);
      g[3+gg] = waveReduceSum(gh);
    }
    if (lane == 0) {
      const int j0 = tt, j1 = D + tt, j2 = 2*D + tt;
      float gir = g[0] + bih[j0], giz = g[1] + bih[j1], gin = g[2] + bih[j2];
      float ghr = g[3] + bhh[j0], ghz = g[4] + bhh[j1], ghn = g[5] + bhh[j2];
      float rr = 1.f / (1.f + __expf(-(gir + ghr)));
      float zz = 1.f / (1.f + __expf(-(giz + ghz)));
      float nn = tanhf(gin + rr * ghn);
      float mn = (1.f - zz)*nn + zz*ms[tt];
      mout[b*D + tt] = mn;
      if (write_out) out[b*D + tt] = mn;
    }
  }
}

extern "C" void kernel_launch(void* const* d_in, const int* in_sizes, int n_in,
                              void* d_out, int out_size, void* d_ws, size_t ws_size,
                              hipStream_t stream) {
  const float* c   = (const float*)d_in[0];
  const float* q   = (const float*)d_in[1];
  const int*   len = (const int*)d_in[2];
  const float* A   = (const float*)d_in[3];
  const float* w1  = (const float*)d_in[4];
  const float* b1  = (const float*)d_in[5];
  const float* w2  = (const float*)d_in[6];
  const float* b2  = (const float*)d_in[7];
  const float* wih = (const float*)d_in[8];
  const float* whh = (const float*)d_in[9];
  const float* bih = (const float*)d_in[10];
  const float* bhh = (const float*)d_in[11];
  float* out = (float*)d_out;

  bf16_t* WCB = (bf16_t*)d_ws;
  bf16_t* WAQ = WCB + (size_t)B*DH;
  bf16_t* WAM = WAQ + DH;
  bf16_t* CBF = WAM + DH;
  bf16_t* AQB = CBF + (size_t)R*D;
  bf16_t* AMB = AQB + (size_t)R*D;
  float* fb = (float*)(AMB + (size_t)R*D);
  float* vq    = fb;
  float* vm    = vq + B*D;
  float* hb    = vm + B*D;
  float* m0    = hb + B*H;
  float* m1    = m0 + B*D;
  float* epart = m1 + B*D;
  float* sc    = epart + (size_t)NCH*B*D;

  k_once<<<DH/256, 256, 0, stream>>>(w1, WAQ, WAM);
  k_prec<<<R*D/2048, 256, 0, stream>>>(c, q, CBF, AQB);
  k_p02<<<B*64, 256, 0, stream>>>(q, A, vq);
  k_minit<<<B, 256, 0, stream>>>(q, m0);

  for (int it = 0; it < 3; ++it) {
    float* min_ = (it & 1) ? m1 : m0;
    float* mout = (it & 1) ? m0 : m1;
    k_pm2<<<B*64, 256, 0, stream>>>(A, w1, b1, q, min_, vm, hb);
    k_comb<<<B*DH/256, 256, 0, stream>>>(w1, q, min_, vq, vm, WCB);
    k_amb<<<R*D/2048, 256, 0, stream>>>(c, min_, AMB);
    k_score3<<<R/64, 256, 0, stream>>>(CBF, AQB, AMB, WCB, WAQ, WAM, hb, w2, b2, sc);
    float* att = out + B*D + (size_t)it*R;
    k_soft<<<B, 1024, 0, stream>>>(sc, len, att);
    k_epart_bf<<<B*NCH, 256, 0, stream>>>(CBF, att, len, epart);
    k_gru2<<<B*16, 256, 0, stream>>>(wih, whh, bih, bhh, epart, min_, mout, out, it == 2 ? 1 : 0);
  }
}

// Round 7
// 180.781 us; speedup vs baseline: 7.2887x; 1.1636x over previous
//
#include <hip/hip_runtime.h>
#include <hip/hip_bf16.h>
#include <math.h>
#include <stdint.h>

#define B 8
#define S 4096
#define D 256
#define H 256
#define FEAT 1794
#define R (B*S)
#define DH (D*H)
#define NCH 64   // s-chunks for e partial reduction

typedef __bf16 bf16_t;
typedef __bf16 bf16x8 __attribute__((ext_vector_type(8)));
typedef float f32x4 __attribute__((ext_vector_type(4)));

#define GLOAD16(gp, lp) __builtin_amdgcn_global_load_lds( \
  (const __attribute__((address_space(1))) void*)(gp), \
  (__attribute__((address_space(3))) void*)(lp), 16, 0, 0)

__device__ __forceinline__ float waveReduceSum(float v) {
  #pragma unroll
  for (int off = 32; off; off >>= 1) v += __shfl_xor(v, off, 64);
  return v;
}

// ---------- once-per-launch kernels ----------

// WAQ[h][k] = w1[h][5D+k], WAM[h][k] = w1[h][6D+k]  (bf16)
__global__ void k_once(const float* __restrict__ w1,
                       bf16_t* __restrict__ WAQ, bf16_t* __restrict__ WAM) {
  int idx = blockIdx.x * 256 + threadIdx.x;   // DH
  int h = idx >> 8, k = idx & 255;
  const float* w1h = w1 + (size_t)h * FEAT;
  WAQ[idx] = (bf16_t)w1h[5*D + k];
  WAM[idx] = (bf16_t)w1h[6*D + k];
}

// CBF = bf16(c), AQB = bf16(|c-q|)
__global__ void k_prec(const float* __restrict__ c, const float* __restrict__ q,
                       bf16_t* __restrict__ CBF, bf16_t* __restrict__ AQB) {
  int gid = blockIdx.x * 256 + threadIdx.x;   // R*D/8
  int r = gid >> 5;
  int k0 = (gid & 31) * 8;
  int b = r >> 12;
  const float* cp = c + (size_t)r*D + k0;
  const float* qp = q + b*D + k0;
  float cv[8], qv[8];
  *(float4*)(cv)   = *(const float4*)(cp);
  *(float4*)(cv+4) = *(const float4*)(cp + 4);
  *(float4*)(qv)   = *(const float4*)(qp);
  *(float4*)(qv+4) = *(const float4*)(qp + 4);
  bf16x8 cb, ab;
  #pragma unroll
  for (int i = 0; i < 8; i++) {
    cb[i] = (bf16_t)cv[i];
    ab[i] = (bf16_t)fabsf(cv[i] - qv[i]);
  }
  *(bf16x8*)(CBF + (size_t)gid*8) = cb;
  *(bf16x8*)(AQB + (size_t)gid*8) = ab;
}

// vq[b][t] = A[t,:] . q[b,:]   — one wave per output
__global__ void k_p02(const float* __restrict__ q, const float* __restrict__ A,
                      float* __restrict__ vq) {
  const int blk = blockIdx.x;              // B*64
  const int b = blk >> 6;
  const int lane = threadIdx.x & 63, wave = threadIdx.x >> 6;
  const int t = (blk & 63)*4 + wave;
  const int l4 = lane * 4;
  float4 q4 = *(const float4*)(q + b*D + l4);
  float4 a4 = *(const float4*)(A + (size_t)t*D + l4);
  float s = a4.x*q4.x + a4.y*q4.y + a4.z*q4.z + a4.w*q4.w;
  s = waveReduceSum(s);
  if (lane == 0) vq[b*D + t] = s;
}

__global__ void k_minit(const float* __restrict__ q, float* __restrict__ m0) {
  m0[blockIdx.x*256 + threadIdx.x] = q[blockIdx.x*256 + threadIdx.x];
}

// ---------- per-hop kernels ----------

// vm[b][t] = A[t,:].m ; hb[b][t] = b1[t] + q.w1[t][2D:3D] + m.w1[t][D:2D]
__global__ void k_pm2(const float* __restrict__ A, const float* __restrict__ w1,
                      const float* __restrict__ b1, const float* __restrict__ q,
                      const float* __restrict__ min_,
                      float* __restrict__ vm, float* __restrict__ hb) {
  const int blk = blockIdx.x;              // B*64
  const int b = blk >> 6;
  const int lane = threadIdx.x & 63, wave = threadIdx.x >> 6;
  const int t = (blk & 63)*4 + wave;
  const int l4 = lane * 4;
  float4 m4 = *(const float4*)(min_ + b*D + l4);
  float4 q4 = *(const float4*)(q + b*D + l4);
  float4 a4 = *(const float4*)(A + (size_t)t*D + l4);
  const float* w1r = w1 + (size_t)t*FEAT;
  float2 wm0 = *(const float2*)(w1r + D + l4);
  float2 wm1 = *(const float2*)(w1r + D + l4 + 2);
  float2 wq0 = *(const float2*)(w1r + 2*D + l4);
  float2 wq1 = *(const float2*)(w1r + 2*D + l4 + 2);
  float sv = a4.x*m4.x + a4.y*m4.y + a4.z*m4.z + a4.w*m4.w;
  float sh = m4.x*wm0.x + m4.y*wm0.y + m4.z*wm1.x + m4.w*wm1.y
           + q4.x*wq0.x + q4.y*wq0.y + q4.z*wq1.x + q4.w*wq1.y;
  sv = waveReduceSum(sv);
  sh = waveReduceSum(sh);
  if (lane == 0) { vm[b*D + t] = sv; hb[b*H + t] = b1[t] + sh; }
}

// WCB[b][h][k] = Wc + q*Wcq + m*Wcm + vq[k]*wdq[h] + vm[k]*wdm[h]  (bf16)
__global__ void k_comb(const float* __restrict__ w1, const float* __restrict__ q,
                       const float* __restrict__ min_,
                       const float* __restrict__ vq, const float* __restrict__ vm,
                       bf16_t* __restrict__ WCB) {
  int idx = blockIdx.x * 256 + threadIdx.x;  // B*DH
  int b = idx >> 16;
  int h = (idx >> 8) & 255;
  int k = idx & 255;
  const float* w1h = w1 + (size_t)h * FEAT;
  float v = w1h[k] + q[b*D + k]*w1h[3*D + k] + min_[b*D + k]*w1h[4*D + k]
          + vq[b*D + k]*w1h[7*D] + vm[b*D + k]*w1h[7*D + 1];
  WCB[idx] = (bf16_t)v;
}

// MFMA score v4: 2-stream LDS-staged A (c, |c-q|), |c-m| computed in-kernel.
// Block: 64 rows x 256 cols, 8 waves (512 thr); each wave owns a 32-col strip.
// LDS A dbuf d: base d*16384; stream s: +s*8192; row r: +r*128;
// physical 16B slot p = logical ^ (r&7).
__global__ __launch_bounds__(512, 4) void k_score4(
    const bf16_t* __restrict__ CBF, const bf16_t* __restrict__ AQB,
    const bf16_t* __restrict__ WCB, const bf16_t* __restrict__ WAQ,
    const bf16_t* __restrict__ WAM, const float* __restrict__ min_,
    const float* __restrict__ hb, const float* __restrict__ w2,
    const float* __restrict__ b2, float* __restrict__ scores) {
  __shared__ char smem[32768];
  __shared__ bf16_t msh[256];
  __shared__ float red[8][64];
  const int t = threadIdx.x;
  const int lane = t & 63, wave = t >> 6;
  const int r0 = blockIdx.x * 64;
  const int b = r0 >> 12;
  const int lrow = lane & 15;
  const int lk = (lane >> 4) * 8;
  const int n0 = wave * 32;

  if (t < 256) msh[t] = (bf16_t)min_[b*D + t];

  const char* cC = (const char*)CBF;
  const char* cQ = (const char*)AQB;
  const bf16_t* bptrC = WCB + (size_t)b*DH;
  const bf16_t* bptrQ = WAQ;
  const bf16_t* bptrM = WAM;

  const int g_off = ((lane >> 3) << 9) + ((((lane & 7) ^ (lane >> 3))) << 4);
  const size_t rowbytes0 = (size_t)r0 << 9;   // r0 * 512B
  const int wave2 = wave * 2;

  f32x4 acc[4][2];
  #pragma unroll
  for (int mi = 0; mi < 4; mi++)
    #pragma unroll
    for (int ni = 0; ni < 2; ni++) acc[mi][ni] = (f32x4){0.f,0.f,0.f,0.f};

  bf16x8 breg[2][6];
  #define LOADB(ks) { \
    const int kelem = (ks)*32 + lk; \
    _Pragma("unroll") \
    for (int ni = 0; ni < 2; ni++) { \
      const size_t co = (size_t)(n0 + ni*16 + lrow) * D + kelem; \
      breg[(ks)&1][ni*3+0] = *(const bf16x8*)(bptrC + co); \
      breg[(ks)&1][ni*3+1] = *(const bf16x8*)(bptrQ + co); \
      breg[(ks)&1][ni*3+2] = *(const bf16x8*)(bptrM + co); \
    } }

  // stage chunk ch (k-bytes ch*128) into dbuf d: 16 regions, 2 per wave
  #define STAGE(ch, d) { \
    const int kbyte = (ch) << 7; \
    _Pragma("unroll") \
    for (int j = 0; j < 2; j++) { \
      const int idx = wave2 + j; \
      const int s_ = idx >> 3; \
      const int r8 = (idx & 7) << 3; \
      const char* gsrc = (s_ ? cQ : cC) \
                       + rowbytes0 + ((size_t)r8 << 9) + kbyte + g_off; \
      GLOAD16(gsrc, smem + (d)*16384 + idx*1024); \
    } }

  LOADB(0);
  STAGE(0, 0);
  __syncthreads();

  #pragma unroll
  for (int ch = 0; ch < 4; ch++) {
    if (ch < 3) STAGE(ch + 1, (ch + 1) & 1);
    #pragma unroll
    for (int kk = 0; kk < 2; kk++) {
      const int ks = ch*2 + kk;
      if (ks < 7) LOADB(ks + 1);
      bf16x8 msl = *(const bf16x8*)(msh + ks*32 + lk);
      float mslf[8];
      #pragma unroll
      for (int i = 0; i < 8; i++) mslf[i] = (float)msl[i];
      const int p = ((kk << 2) + (lane >> 4)) ^ (lane & 7);
      const char* lb = smem + (ch & 1)*16384;
      #pragma unroll
      for (int mi = 0; mi < 4; mi++) {
        const int ro = (mi*16 + lrow)*128 + p*16;
        bf16x8 ac = *(const bf16x8*)(lb + ro);
        bf16x8 aq = *(const bf16x8*)(lb + 8192 + ro);
        bf16x8 am;
        #pragma unroll
        for (int i = 0; i < 8; i++) am[i] = (bf16_t)fabsf((float)ac[i] - mslf[i]);
        #pragma unroll
        for (int ni = 0; ni < 2; ni++) {
          acc[mi][ni] = __builtin_amdgcn_mfma_f32_16x16x32_bf16(ac, breg[ks&1][ni*3+0], acc[mi][ni], 0, 0, 0);
          acc[mi][ni] = __builtin_amdgcn_mfma_f32_16x16x32_bf16(aq, breg[ks&1][ni*3+1], acc[mi][ni], 0, 0, 0);
          acc[mi][ni] = __builtin_amdgcn_mfma_f32_16x16x32_bf16(am, breg[ks&1][ni*3+2], acc[mi][ni], 0, 0, 0);
        }
      }
    }
    __syncthreads();
  }

  // epilogue: tanh + w2-dot, reduce over h (layout verified rounds 4-6)
  float hbv[2], w2v[2];
  #pragma unroll
  for (int ni = 0; ni < 2; ni++) {
    const int col = n0 + ni*16 + lrow;
    hbv[ni] = hb[b*H + col];
    w2v[ni] = w2[col];
  }
  #pragma unroll
  for (int mi = 0; mi < 4; mi++) {
    #pragma unroll
    for (int j = 0; j < 4; j++) {
      float ps = 0.f;
      #pragma unroll
      for (int ni = 0; ni < 2; ni++) {
        float x = acc[mi][ni][j] + hbv[ni];
        float ex = __expf(2.f * x);
        float th = 1.f - 2.f * __builtin_amdgcn_rcpf(ex + 1.f);
        ps += th * w2v[ni];
      }
      ps += __shfl_xor(ps, 1, 64);
      ps += __shfl_xor(ps, 2, 64);
      ps += __shfl_xor(ps, 4, 64);
      ps += __shfl_xor(ps, 8, 64);
      if (lrow == 0) red[wave][mi*16 + (lane >> 4)*4 + j] = ps;
    }
  }
  __syncthreads();
  if (t < 64) {
    float s = red[0][t] + red[1][t] + red[2][t] + red[3][t]
            + red[4][t] + red[5][t] + red[6][t] + red[7][t] + b2[0];
    scores[r0 + t] = s;
  }
}

// Masked softmax over S per batch.
__global__ __launch_bounds__(1024) void k_soft(const float* __restrict__ scores,
                                               const int* __restrict__ len_c,
                                               float* __restrict__ att) {
  const int b = blockIdx.x, t = threadIdx.x;
  const int len = len_c[b];
  __shared__ float rbuf[16];
  const float* sc = scores + b*S;
  float mx = -1e30f;
  for (int s = t; s < len; s += 1024) mx = fmaxf(mx, sc[s]);
  #pragma unroll
  for (int off = 32; off; off >>= 1) mx = fmaxf(mx, __shfl_xor(mx, off, 64));
  if ((t & 63) == 0) rbuf[t >> 6] = mx;
  __syncthreads();
  mx = rbuf[0];
  #pragma unroll
  for (int i = 1; i < 16; i++) mx = fmaxf(mx, rbuf[i]);
  __syncthreads();
  float sum = 0.f;
  float* ab = att + b*S;
  for (int s = t; s < S; s += 1024) {
    if (s < len) { float e = __expf(sc[s] - mx); ab[s] = e; sum += e; }
    else ab[s] = 0.f;
  }
  sum = waveReduceSum(sum);
  if ((t & 63) == 0) rbuf[t >> 6] = sum;
  __syncthreads();
  sum = 0.f;
  #pragma unroll
  for (int i = 0; i < 16; i++) sum += rbuf[i];
  const float inv = 1.f / sum;
  for (int s = t; s < len; s += 1024) ab[s] *= inv;
}

// epart from bf16 c — lanes read consecutive 2B: coalesced.
__global__ void k_epart_bf(const bf16_t* __restrict__ CBF, const float* __restrict__ att,
                           const int* __restrict__ len_c, float* __restrict__ epart) {
  const int b = blockIdx.x >> 6, ch = blockIdx.x & 63;
  const int t = threadIdx.x;
  const int len = len_c[b];
  const int s0 = ch * (S / NCH);
  const int send = min(s0 + (S / NCH), len);
  float acc = 0.f;
  const float* ab = att + b*S;
  int s = s0;
  for (; s + 3 < send; s += 4) {
    float a0 = ab[s], a1 = ab[s+1], a2 = ab[s+2], a3 = ab[s+3];
    const bf16_t* cp = CBF + (size_t)(b*S + s)*D + t;
    acc += a0*(float)cp[0] + a1*(float)cp[D] + a2*(float)cp[2*D] + a3*(float)cp[3*D];
  }
  for (; s < send; s++) acc += ab[s] * (float)CBF[(size_t)(b*S + s)*D + t];
  epart[(ch*B + b)*D + t] = acc;
}

// GRU: es = sum(epart); 6 coalesced wave-dots per t; gates elementwise.
__global__ __launch_bounds__(256) void k_gru2(
    const float* __restrict__ wih, const float* __restrict__ whh,
    const float* __restrict__ bih, const float* __restrict__ bhh,
    const float* __restrict__ epart, const float* __restrict__ min_,
    float* __restrict__ mout, float* __restrict__ out, const int write_out) {
  const int blk = blockIdx.x;         // B*16
  const int b = blk >> 4;
  const int t0 = (blk & 15) << 4;
  const int t = threadIdx.x;
  const int lane = t & 63, wave = t >> 6;
  __shared__ float es[D], ms[D];
  float e = 0.f;
  #pragma unroll
  for (int ch = 0; ch < NCH; ch++) e += epart[(ch*B + b)*D + t];
  es[t] = e;
  ms[t] = min_[b*D + t];
  __syncthreads();
  const int l4 = lane * 4;
  float4 e4 = *(const float4*)(es + l4);
  float4 m4 = *(const float4*)(ms + l4);
  #pragma unroll
  for (int tl = 0; tl < 4; tl++) {
    const int tt = t0 + wave*4 + tl;
    float g[6];
    #pragma unroll
    for (int gg = 0; gg < 3; gg++) {
      const int j = gg*D + tt;
      const float4 wi4 = *(const float4*)(wih + (size_t)j*D + l4);
      const float4 wh4 = *(const float4*)(whh + (size_t)j*D + l4);
      float gi = e4.x*wi4.x + e4.y*wi4.y + e4.z*wi4.z + e4.w*wi4.w;
      float gh = m4.x*wh4.x + m4.y*wh4.y + m4.z*wh4.z + m4.w*wh4.w;
      g[gg]   = waveReduceSum(gi);
      g[3+gg] = waveReduceSum(gh);
    }
    if (lane == 0) {
      const int j0 = tt, j1 = D + tt, j2 = 2*D + tt;
      float gir = g[0] + bih[j0], giz = g[1] + bih[j1], gin = g[2] + bih[j2];
      float ghr = g[3] + bhh[j0], ghz = g[4] + bhh[j1], ghn = g[5] + bhh[j2];
      float rr = 1.f / (1.f + __expf(-(gir + ghr)));
      float zz = 1.f / (1.f + __expf(-(giz + ghz)));
      float nn = tanhf(gin + rr * ghn);
      float mn = (1.f - zz)*nn + zz*ms[tt];
      mout[b*D + tt] = mn;
      if (write_out) out[b*D + tt] = mn;
    }
  }
}

extern "C" void kernel_launch(void* const* d_in, const int* in_sizes, int n_in,
                              void* d_out, int out_size, void* d_ws, size_t ws_size,
                              hipStream_t stream) {
  const float* c   = (const float*)d_in[0];
  const float* q   = (const float*)d_in[1];
  const int*   len = (const int*)d_in[2];
  const float* A   = (const float*)d_in[3];
  const float* w1  = (const float*)d_in[4];
  const float* b1  = (const float*)d_in[5];
  const float* w2  = (const float*)d_in[6];
  const float* b2  = (const float*)d_in[7];
  const float* wih = (const float*)d_in[8];
  const float* whh = (const float*)d_in[9];
  const float* bih = (const float*)d_in[10];
  const float* bhh = (const float*)d_in[11];
  float* out = (float*)d_out;

  bf16_t* WCB = (bf16_t*)d_ws;
  bf16_t* WAQ = WCB + (size_t)B*DH;
  bf16_t* WAM = WAQ + DH;
  bf16_t* CBF = WAM + DH;
  bf16_t* AQB = CBF + (size_t)R*D;
  float* fb = (float*)(AQB + (size_t)R*D);
  float* vq    = fb;
  float* vm    = vq + B*D;
  float* hb    = vm + B*D;
  float* m0    = hb + B*H;
  float* m1    = m0 + B*D;
  float* epart = m1 + B*D;
  float* sc    = epart + (size_t)NCH*B*D;

  k_once<<<DH/256, 256, 0, stream>>>(w1, WAQ, WAM);
  k_prec<<<R*D/2048, 256, 0, stream>>>(c, q, CBF, AQB);
  k_p02<<<B*64, 256, 0, stream>>>(q, A, vq);
  k_minit<<<B, 256, 0, stream>>>(q, m0);

  for (int it = 0; it < 3; ++it) {
    float* min_ = (it & 1) ? m1 : m0;
    float* mout = (it & 1) ? m0 : m1;
    k_pm2<<<B*64, 256, 0, stream>>>(A, w1, b1, q, min_, vm, hb);
    k_comb<<<B*DH/256, 256, 0, stream>>>(w1, q, min_, vq, vm, WCB);
    k_score4<<<R/64, 512, 0, stream>>>(CBF, AQB, WCB, WAQ, WAM, min_, hb, w2, b2, sc);
    float* att = out + B*D + (size_t)it*R;
    k_soft<<<B, 1024, 0, stream>>>(sc, len, att);
    k_epart_bf<<<B*NCH, 256, 0, stream>>>(CBF, att, len, epart);
    k_gru2<<<B*16, 256, 0, stream>>>(wih, whh, bih, bhh, epart, min_, mout, out, it == 2 ? 1 : 0);
  }
}